// Round 1
// baseline (213.704 us; speedup 1.0000x reference)
//
#include <hip/hip_runtime.h>
#include <hip/hip_bf16.h>

typedef unsigned short u16;
typedef unsigned int u32;
typedef __bf16 bf16x8 __attribute__((ext_vector_type(8)));
typedef float f32x4 __attribute__((ext_vector_type(4)));
typedef unsigned int u32x4 __attribute__((ext_vector_type(4)));
typedef unsigned int u32x2 __attribute__((ext_vector_type(2)));

#define NN 512
#define LL 40
#define DD 128
#define OO 256
#define KK 9
#define MHCL 34
#define TT 32
#define OC 32      // o-chunk per oc-iteration
#define OCPB 2     // oc iterations per block (oc-quarter) -> grid = NN*4
#define PSTR 136   // pept LDS row stride (u16)
#define MSTR 72    // mhcT LDS row stride (u16)
#define KSTR 136   // kern LDS row stride (u16)
#define LPAD 64    // padded l-dim for MFMA K
#define WPADL 64   // padded l-dim in preconverted W

#define PEPT_U16 (LL * PSTR)   // 5440 u16 = 10880 B
#define KERN_U16 (32 * KSTR)   // 4352 u16 =  8704 B (also holds red2: 2*32*33*4 = 8448 B)

__device__ __forceinline__ u16 f2bf(float x) {
    unsigned int u = __builtin_bit_cast(unsigned int, x);
    u = (u + 0x7FFFu + ((u >> 16) & 1u)) >> 16;
    return (u16)u;
}
__device__ __forceinline__ u32 pk2(float a, float b) {
    __hip_bfloat162 h = __float22bfloat162_rn(make_float2(a, b)); // x = low half
    u32 r;
    __builtin_memcpy(&r, &h, 4);
    return r;
}
__device__ __forceinline__ bf16x8 lds_read8(const u16* p) {
    u32x4 r;
    __builtin_memcpy(&r, __builtin_assume_aligned(p, 16), 16);
    return __builtin_bit_cast(bf16x8, r);
}
__device__ __forceinline__ f32x4 mfma16(bf16x8 a, bf16x8 b, f32x4 c) {
    return __builtin_amdgcn_mfma_f32_16x16x32_bf16(a, b, c, 0, 0, 0);
}

// prologue: W fp32 [O][K][34] -> bf16 zero-padded [O][K][64] in ws
__global__ void w_convert(const float* __restrict__ wgt, u32* __restrict__ wp) {
    int i = blockIdx.x * 256 + threadIdx.x;        // 36864 u32 outputs
    if (i >= OO * KK * (WPADL / 2)) return;
    int o = i / (KK * (WPADL / 2));
    int r = i - o * (KK * (WPADL / 2));
    int k = r >> 5;
    int lp = (r & 31) << 1;
    const float* src = wgt + ((size_t)o * KK + k) * MHCL;
    float a = (lp     < MHCL) ? src[lp]     : 0.f;
    float b = (lp + 1 < MHCL) ? src[lp + 1] : 0.f;
    wp[i] = pk2(a, b);
}

template<bool PRE>
__global__ __launch_bounds__(256, 8)
void iconv_kernel(const float* __restrict__ pept,
                  const float* __restrict__ mhc,
                  const float* __restrict__ wgt,
                  const u16* __restrict__ wp,
                  const float* __restrict__ bias,
                  float* __restrict__ out)
{
    // LDS: 19584 B -> 8 blocks/CU with launch_bounds(256,8).
    // Union lifetimes: [0,18432) mhcT[128][72] (staging only) ->
    //   [0,10880) pept[40][136]  |  [10880,19584) kern[32][136] / red2 f32[2][32][33]
    __shared__ __align__(16) u16 s_mem[PEPT_U16 + KERN_U16];

    const int tid  = threadIdx.x;
    const int wave = tid >> 6;
    const int lane = tid & 63;
    const int quad = lane >> 4;
    const int l16  = lane & 15;

    const int n    = blockIdx.x >> 2;          // 4 blocks per sample
    const int oc_q = blockIdx.x & 3;           // each does 2 of the 8 o-chunks

    u16* const s_pept = s_mem;
    u16* const kb     = s_mem + PEPT_U16;

    // ---- stage A: mhcT [128][MSTR] bf16, l zero-padded to 64, vectorized b128 writes ----
    {
        const float* mg = mhc + (size_t)n * MHCL * DD;
        #pragma unroll 1
        for (int i = tid; i < DD * (LPAD / 8); i += 256) {   // 1024 items, g wave-uniform
            int g = i >> 7, d = i & 127;
            u32x4 hh;
            #pragma unroll
            for (int jj = 0; jj < 4; ++jj) {
                int l = g * 8 + jj * 2;
                float a = (l     < MHCL) ? mg[(size_t)l * DD + d]       : 0.f;
                float b = (l + 1 < MHCL) ? mg[(size_t)(l + 1) * DD + d] : 0.f;
                hh[jj] = pk2(a, b);
            }
            __builtin_memcpy(__builtin_assume_aligned(&s_mem[d * MSTR + g * 8], 16), &hh, 16);
        }
    }
    __syncthreads();

    // ---- k-invariant mhc A-fragments into registers: wave owns d in [wave*32, wave*32+32) ----
    bf16x8 aF[2][2];   // [nt-local][ki]; A[m=d][kdim=l]
    #pragma unroll
    for (int ntl = 0; ntl < 2; ++ntl) {
        const int d = (wave * 2 + ntl) * 16 + l16;
        aF[ntl][0] = lds_read8(&s_mem[d * MSTR + quad * 8]);
        aF[ntl][1] = lds_read8(&s_mem[d * MSTR + 32 + quad * 8]);
    }
    __syncthreads();   // mhcT region dead -> pept + kern buffers may overwrite

    // ---- stage B: pept fp32 -> bf16 ----
    {
        const float* pg = pept + (size_t)n * LL * DD;
        #pragma unroll 1
        for (int i = tid; i < (LL * DD) / 4; i += 256) {
            int row = i >> 5, c4 = (i & 31) << 2;
            f32x4 v;
            __builtin_memcpy(&v, __builtin_assume_aligned(pg + row * DD + c4, 16), 16);
            u32x2 h = { pk2(v[0], v[1]), pk2(v[2], v[3]) };
            __builtin_memcpy(__builtin_assume_aligned(&s_pept[row * PSTR + c4], 8), &h, 8);
        }
    }
    __syncthreads();

    auto loadW = [&](int o_base, int k, bf16x8 wF[2][2]) {
        if (PRE) {
            #pragma unroll
            for (int mt = 0; mt < 2; ++mt) {
                const u16* wr = wp + ((size_t)(o_base + mt * 16 + l16) * KK + k) * WPADL;
                u32x4 r0, r1;
                __builtin_memcpy(&r0, __builtin_assume_aligned(wr + quad * 8, 16), 16);
                __builtin_memcpy(&r1, __builtin_assume_aligned(wr + 32 + quad * 8, 16), 16);
                wF[mt][0] = __builtin_bit_cast(bf16x8, r0);
                wF[mt][1] = __builtin_bit_cast(bf16x8, r1);
            }
        } else {
            #pragma unroll
            for (int mt = 0; mt < 2; ++mt) {
                const float* wrow = wgt + ((size_t)(o_base + mt * 16 + l16) * KK + k) * MHCL;
                float w8[8];
                __builtin_memcpy(w8, __builtin_assume_aligned(wrow + quad * 8, 8), 32);
                u16 h0[8];
                #pragma unroll
                for (int j = 0; j < 8; ++j) h0[j] = f2bf(w8[j]);
                __builtin_memcpy(&wF[mt][0], h0, 16);
                u16 h1[8] = {0,0,0,0,0,0,0,0};
                if (quad == 0) { h1[0] = f2bf(wrow[32]); h1[1] = f2bf(wrow[33]); }
                __builtin_memcpy(&wF[mt][1], h1, 16);
            }
        }
    };

    // stage1: wave computes kern rows (all o') for its d-columns [32*wave, 32*wave+32) — private region
    auto stage1 = [&](const bf16x8 wF[2][2]) {
        #pragma unroll
        for (int ntl = 0; ntl < 2; ++ntl) {
            const int nt = wave * 2 + ntl;
            f32x4 c0 = {0.f,0.f,0.f,0.f}, c1 = c0;
            #pragma unroll
            for (int ki = 0; ki < 2; ++ki) {
                c0 = mfma16(aF[ntl][ki], wF[0][ki], c0);   // C[d_local][o' 0..15]
                c1 = mfma16(aF[ntl][ki], wF[1][ki], c1);   // C[d_local][o' 16..31]
            }
            u32x2 p0 = { pk2(fmaxf(c0[0], 0.f), fmaxf(c0[1], 0.f)),
                         pk2(fmaxf(c0[2], 0.f), fmaxf(c0[3], 0.f)) };
            u32x2 p1 = { pk2(fmaxf(c1[0], 0.f), fmaxf(c1[1], 0.f)),
                         pk2(fmaxf(c1[2], 0.f), fmaxf(c1[3], 0.f)) };
            __builtin_memcpy(__builtin_assume_aligned(&kb[l16 * KSTR + nt * 16 + quad * 4], 8), &p0, 8);
            __builtin_memcpy(__builtin_assume_aligned(&kb[(16 + l16) * KSTR + nt * 16 + quad * 4], 8), &p1, 8);
        }
    };

    const int off = wave * 32 + quad * 8;   // this wave's d-chunk column offset

    #pragma unroll 1
    for (int oci = 0; oci < OCPB; ++oci) {
        const int o_base = (oc_q * OCPB + oci) * OC;
        // acc_ij[r] = out[t = i*16 + quad*4 + r][o' = j*16 + l16], partial over d-chunk = wave
        f32x4 acc00 = {0.f,0.f,0.f,0.f}, acc01 = acc00, acc10 = acc00, acc11 = acc00;

        {
            bf16x8 wF0[2][2];
            loadW(o_base, 0, wF0);
            stage1(wF0);
        }

        // NO barriers: wave reads exactly the kern columns it wrote; same-wave LDS deps
        // are ordered by lgkmcnt. Waves drift freely -> latency pipelining across k.
        for (int k = 0; k < KK; ++k) {
            bf16x8 wFn[2][2];
            if (k < KK - 1) loadW(o_base, k + 1, wFn);   // issue global loads early
            // stage 2: A=pept (m=t), B=kern (n=o'), kdim = this wave's 32 d
            bf16x8 bk0 = lds_read8(&kb[l16 * KSTR + off]);
            bf16x8 bk1 = lds_read8(&kb[(16 + l16) * KSTR + off]);
            bf16x8 ap0 = lds_read8(&s_pept[(k + l16) * PSTR + off]);
            bf16x8 ap1 = lds_read8(&s_pept[(k + 16 + l16) * PSTR + off]);
            acc00 = mfma16(ap0, bk0, acc00);
            acc01 = mfma16(ap0, bk1, acc01);
            acc10 = mfma16(ap1, bk0, acc10);
            acc11 = mfma16(ap1, bk1, acc11);
            if (k < KK - 1) stage1(wFn);                 // overwrite own columns for k+1
        }

        __syncthreads();   // all waves done with kern/stage2 before red2 tramples kb
        // ---- cross-wave (d-chunk) reduction, 2-step into red2 = f32[2][t=32][o'=33] ----
        float* red = (float*)kb;
        if (wave < 2) {
            float* rw = red + wave * (TT * 33);
            #pragma unroll
            for (int r = 0; r < 4; ++r) {
                rw[(quad * 4 + r) * 33 + l16]           = acc00[r];
                rw[(quad * 4 + r) * 33 + 16 + l16]      = acc01[r];
                rw[(16 + quad * 4 + r) * 33 + l16]      = acc10[r];
                rw[(16 + quad * 4 + r) * 33 + 16 + l16] = acc11[r];
            }
        }
        __syncthreads();
        if (wave >= 2) {      // disjoint buffers: wave2 -> buf0, wave3 -> buf1 (race-free RMW)
            float* rw = red + (wave - 2) * (TT * 33);
            #pragma unroll
            for (int r = 0; r < 4; ++r) {
                rw[(quad * 4 + r) * 33 + l16]           += acc00[r];
                rw[(quad * 4 + r) * 33 + 16 + l16]      += acc01[r];
                rw[(16 + quad * 4 + r) * 33 + l16]      += acc10[r];
                rw[(16 + quad * 4 + r) * 33 + 16 + l16] += acc11[r];
            }
        }
        __syncthreads();

        {
            const int o  = tid >> 3;        // 0..31
            const int t0 = (tid & 7) * 4;   // 0,4,...,28
            const float bv = bias[o_base + o];
            f32x4 res;
            #pragma unroll
            for (int j = 0; j < 4; ++j) {
                int idx = (t0 + j) * 33 + o;
                res[j] = red[idx] + red[TT * 33 + idx] + bv;
            }
            float* op = out + ((size_t)n * OO + o_base + o) * TT + t0;
            __builtin_memcpy(__builtin_assume_aligned(op, 16), &res, 16);
        }
        __syncthreads();   // red reads drained before next oc's stage1 writes kern region
    }
}

extern "C" void kernel_launch(void* const* d_in, const int* in_sizes, int n_in,
                              void* d_out, int out_size, void* d_ws, size_t ws_size,
                              hipStream_t stream) {
    const float* pept = (const float*)d_in[0];
    const float* mhc  = (const float*)d_in[1];
    const float* wgt  = (const float*)d_in[2];
    const float* bias = (const float*)d_in[3];
    float* out = (float*)d_out;
    dim3 block(256);             // 4 waves

    const size_t w_bytes = (size_t)OO * KK * WPADL * sizeof(u16); // 294,912
    if (ws_size >= w_bytes) {
        w_convert<<<dim3((OO * KK * (WPADL / 2) + 255) / 256), block, 0, stream>>>(wgt, (u32*)d_ws);
        iconv_kernel<true><<<dim3(NN * 4), block, 0, stream>>>(pept, mhc, wgt, (const u16*)d_ws, bias, out);
    } else {
        iconv_kernel<false><<<dim3(NN * 4), block, 0, stream>>>(pept, mhc, wgt, nullptr, bias, out);
    }
}

// Round 2
// 169.053 us; speedup vs baseline: 1.2641x; 1.2641x over previous
//
#include <hip/hip_runtime.h>
#include <hip/hip_bf16.h>

typedef unsigned short u16;
typedef unsigned int u32;
typedef __bf16 bf16x8 __attribute__((ext_vector_type(8)));
typedef float f32x4 __attribute__((ext_vector_type(4)));
typedef unsigned int u32x4 __attribute__((ext_vector_type(4)));
typedef unsigned int u32x2 __attribute__((ext_vector_type(2)));

#define NN 512
#define LL 40
#define DD 128
#define OO 256
#define KK 9
#define MHCL 34
#define TT 32
#define OC 32      // o-chunk per oc-iteration
#define OCPB 2     // oc iterations per block (oc-quarter) -> grid = NN*4
#define PSTR 136   // pept LDS row stride (u16)
#define MSTR 72    // mhcT LDS row stride (u16)
#define KSTR 136   // kern LDS row stride (u16)
#define LPAD 64    // padded l-dim for MFMA K
#define WPADL 64   // padded l-dim in preconverted W

#define PEPT_U16 (LL * PSTR)   // 5440 u16 = 10880 B
#define KERN_U16 (32 * KSTR)   // 4352 u16 =  8704 B (also holds red2: 2*32*33*4 = 8448 B)

__device__ __forceinline__ u16 f2bf(float x) {
    unsigned int u = __builtin_bit_cast(unsigned int, x);
    u = (u + 0x7FFFu + ((u >> 16) & 1u)) >> 16;
    return (u16)u;
}
__device__ __forceinline__ u32 pk2(float a, float b) {
    __hip_bfloat162 h = __float22bfloat162_rn(make_float2(a, b)); // x = low half
    u32 r;
    __builtin_memcpy(&r, &h, 4);
    return r;
}
__device__ __forceinline__ bf16x8 lds_read8(const u16* p) {
    u32x4 r;
    __builtin_memcpy(&r, __builtin_assume_aligned(p, 16), 16);
    return __builtin_bit_cast(bf16x8, r);
}
__device__ __forceinline__ f32x4 mfma16(bf16x8 a, bf16x8 b, f32x4 c) {
    return __builtin_amdgcn_mfma_f32_16x16x32_bf16(a, b, c, 0, 0, 0);
}

// prologue: W fp32 [O][K][34] -> bf16 zero-padded [O][K][64] in ws
__global__ void w_convert(const float* __restrict__ wgt, u32* __restrict__ wp) {
    int i = blockIdx.x * 256 + threadIdx.x;        // 36864 u32 outputs
    if (i >= OO * KK * (WPADL / 2)) return;
    int o = i / (KK * (WPADL / 2));
    int r = i - o * (KK * (WPADL / 2));
    int k = r >> 5;
    int lp = (r & 31) << 1;
    const float* src = wgt + ((size_t)o * KK + k) * MHCL;
    float a = (lp     < MHCL) ? src[lp]     : 0.f;
    float b = (lp + 1 < MHCL) ? src[lp + 1] : 0.f;
    wp[i] = pk2(a, b);
}

// launch_bounds(256,6): VGPR cap 85/wave. (256,8) capped at 64 and SPILLED:
// WRITE_SIZE 16->203 MB, FETCH 19.6->115 MB, MfmaUtil 13->7%, dur 82->157us.
// Natural demand ~44-70 fits under 85; occupancy then set by LDS (19.5KB -> 8
// blocks/CU max) and actual VGPR use, not by the allocator cap.
template<bool PRE>
__global__ __launch_bounds__(256, 6)
void iconv_kernel(const float* __restrict__ pept,
                  const float* __restrict__ mhc,
                  const float* __restrict__ wgt,
                  const u16* __restrict__ wp,
                  const float* __restrict__ bias,
                  float* __restrict__ out)
{
    // LDS: 19584 B.
    // Union lifetimes: [0,18432) mhcT[128][72] (staging only) ->
    //   [0,10880) pept[40][136]  |  [10880,19584) kern[32][136] / red2 f32[2][32][33]
    __shared__ __align__(16) u16 s_mem[PEPT_U16 + KERN_U16];

    const int tid  = threadIdx.x;
    const int wave = tid >> 6;
    const int lane = tid & 63;
    const int quad = lane >> 4;
    const int l16  = lane & 15;

    const int n    = blockIdx.x >> 2;          // 4 blocks per sample
    const int oc_q = blockIdx.x & 3;           // each does 2 of the 8 o-chunks

    u16* const s_pept = s_mem;
    u16* const kb     = s_mem + PEPT_U16;

    // ---- stage A: mhcT [128][MSTR] bf16, l zero-padded to 64, vectorized b128 writes ----
    {
        const float* mg = mhc + (size_t)n * MHCL * DD;
        #pragma unroll 1
        for (int i = tid; i < DD * (LPAD / 8); i += 256) {   // 1024 items, g wave-uniform
            int g = i >> 7, d = i & 127;
            u32x4 hh;
            #pragma unroll
            for (int jj = 0; jj < 4; ++jj) {
                int l = g * 8 + jj * 2;
                float a = (l     < MHCL) ? mg[(size_t)l * DD + d]       : 0.f;
                float b = (l + 1 < MHCL) ? mg[(size_t)(l + 1) * DD + d] : 0.f;
                hh[jj] = pk2(a, b);
            }
            __builtin_memcpy(__builtin_assume_aligned(&s_mem[d * MSTR + g * 8], 16), &hh, 16);
        }
    }
    __syncthreads();

    // ---- k-invariant mhc A-fragments into registers: wave owns d in [wave*32, wave*32+32) ----
    bf16x8 aF[2][2];   // [nt-local][ki]; A[m=d][kdim=l]
    #pragma unroll
    for (int ntl = 0; ntl < 2; ++ntl) {
        const int d = (wave * 2 + ntl) * 16 + l16;
        aF[ntl][0] = lds_read8(&s_mem[d * MSTR + quad * 8]);
        aF[ntl][1] = lds_read8(&s_mem[d * MSTR + 32 + quad * 8]);
    }
    __syncthreads();   // mhcT region dead -> pept + kern buffers may overwrite

    // ---- stage B: pept fp32 -> bf16 ----
    {
        const float* pg = pept + (size_t)n * LL * DD;
        #pragma unroll 1
        for (int i = tid; i < (LL * DD) / 4; i += 256) {
            int row = i >> 5, c4 = (i & 31) << 2;
            f32x4 v;
            __builtin_memcpy(&v, __builtin_assume_aligned(pg + row * DD + c4, 16), 16);
            u32x2 h = { pk2(v[0], v[1]), pk2(v[2], v[3]) };
            __builtin_memcpy(__builtin_assume_aligned(&s_pept[row * PSTR + c4], 8), &h, 8);
        }
    }
    __syncthreads();

    auto loadW = [&](int o_base, int k, bf16x8 wF[2][2]) {
        if (PRE) {
            #pragma unroll
            for (int mt = 0; mt < 2; ++mt) {
                const u16* wr = wp + ((size_t)(o_base + mt * 16 + l16) * KK + k) * WPADL;
                u32x4 r0, r1;
                __builtin_memcpy(&r0, __builtin_assume_aligned(wr + quad * 8, 16), 16);
                __builtin_memcpy(&r1, __builtin_assume_aligned(wr + 32 + quad * 8, 16), 16);
                wF[mt][0] = __builtin_bit_cast(bf16x8, r0);
                wF[mt][1] = __builtin_bit_cast(bf16x8, r1);
            }
        } else {
            #pragma unroll
            for (int mt = 0; mt < 2; ++mt) {
                const float* wrow = wgt + ((size_t)(o_base + mt * 16 + l16) * KK + k) * MHCL;
                float w8[8];
                __builtin_memcpy(w8, __builtin_assume_aligned(wrow + quad * 8, 8), 32);
                u16 h0[8];
                #pragma unroll
                for (int j = 0; j < 8; ++j) h0[j] = f2bf(w8[j]);
                __builtin_memcpy(&wF[mt][0], h0, 16);
                u16 h1[8] = {0,0,0,0,0,0,0,0};
                if (quad == 0) { h1[0] = f2bf(wrow[32]); h1[1] = f2bf(wrow[33]); }
                __builtin_memcpy(&wF[mt][1], h1, 16);
            }
        }
    };

    // stage1: wave computes kern rows (all o') for its d-columns [32*wave, 32*wave+32) — private region
    auto stage1 = [&](const bf16x8 wF[2][2]) {
        #pragma unroll
        for (int ntl = 0; ntl < 2; ++ntl) {
            const int nt = wave * 2 + ntl;
            f32x4 c0 = {0.f,0.f,0.f,0.f}, c1 = c0;
            #pragma unroll
            for (int ki = 0; ki < 2; ++ki) {
                c0 = mfma16(aF[ntl][ki], wF[0][ki], c0);   // C[d_local][o' 0..15]
                c1 = mfma16(aF[ntl][ki], wF[1][ki], c1);   // C[d_local][o' 16..31]
            }
            u32x2 p0 = { pk2(fmaxf(c0[0], 0.f), fmaxf(c0[1], 0.f)),
                         pk2(fmaxf(c0[2], 0.f), fmaxf(c0[3], 0.f)) };
            u32x2 p1 = { pk2(fmaxf(c1[0], 0.f), fmaxf(c1[1], 0.f)),
                         pk2(fmaxf(c1[2], 0.f), fmaxf(c1[3], 0.f)) };
            __builtin_memcpy(__builtin_assume_aligned(&kb[l16 * KSTR + nt * 16 + quad * 4], 8), &p0, 8);
            __builtin_memcpy(__builtin_assume_aligned(&kb[(16 + l16) * KSTR + nt * 16 + quad * 4], 8), &p1, 8);
        }
    };

    const int off = wave * 32 + quad * 8;   // this wave's d-chunk column offset

    #pragma unroll 1
    for (int oci = 0; oci < OCPB; ++oci) {
        const int o_base = (oc_q * OCPB + oci) * OC;
        // acc_ij[r] = out[t = i*16 + quad*4 + r][o' = j*16 + l16], partial over d-chunk = wave
        f32x4 acc00 = {0.f,0.f,0.f,0.f}, acc01 = acc00, acc10 = acc00, acc11 = acc00;

        {
            bf16x8 wF0[2][2];
            loadW(o_base, 0, wF0);
            stage1(wF0);
        }

        // NO barriers: wave reads exactly the kern columns it wrote; same-wave LDS deps
        // are ordered by lgkmcnt. Waves drift freely -> latency pipelining across k.
        for (int k = 0; k < KK; ++k) {
            bf16x8 wFn[2][2];
            if (k < KK - 1) loadW(o_base, k + 1, wFn);   // issue global loads early
            // stage 2: A=pept (m=t), B=kern (n=o'), kdim = this wave's 32 d
            bf16x8 bk0 = lds_read8(&kb[l16 * KSTR + off]);
            bf16x8 bk1 = lds_read8(&kb[(16 + l16) * KSTR + off]);
            bf16x8 ap0 = lds_read8(&s_pept[(k + l16) * PSTR + off]);
            bf16x8 ap1 = lds_read8(&s_pept[(k + 16 + l16) * PSTR + off]);
            acc00 = mfma16(ap0, bk0, acc00);
            acc01 = mfma16(ap0, bk1, acc01);
            acc10 = mfma16(ap1, bk0, acc10);
            acc11 = mfma16(ap1, bk1, acc11);
            if (k < KK - 1) stage1(wFn);                 // overwrite own columns for k+1
        }

        __syncthreads();   // all waves done with kern/stage2 before red2 tramples kb
        // ---- cross-wave (d-chunk) reduction, 2-step into red2 = f32[2][t=32][o'=33] ----
        float* red = (float*)kb;
        if (wave < 2) {
            float* rw = red + wave * (TT * 33);
            #pragma unroll
            for (int r = 0; r < 4; ++r) {
                rw[(quad * 4 + r) * 33 + l16]           = acc00[r];
                rw[(quad * 4 + r) * 33 + 16 + l16]      = acc01[r];
                rw[(16 + quad * 4 + r) * 33 + l16]      = acc10[r];
                rw[(16 + quad * 4 + r) * 33 + 16 + l16] = acc11[r];
            }
        }
        __syncthreads();
        if (wave >= 2) {      // disjoint buffers: wave2 -> buf0, wave3 -> buf1 (race-free RMW)
            float* rw = red + (wave - 2) * (TT * 33);
            #pragma unroll
            for (int r = 0; r < 4; ++r) {
                rw[(quad * 4 + r) * 33 + l16]           += acc00[r];
                rw[(quad * 4 + r) * 33 + 16 + l16]      += acc01[r];
                rw[(16 + quad * 4 + r) * 33 + l16]      += acc10[r];
                rw[(16 + quad * 4 + r) * 33 + 16 + l16] += acc11[r];
            }
        }
        __syncthreads();

        {
            const int o  = tid >> 3;        // 0..31
            const int t0 = (tid & 7) * 4;   // 0,4,...,28
            const float bv = bias[o_base + o];
            f32x4 res;
            #pragma unroll
            for (int j = 0; j < 4; ++j) {
                int idx = (t0 + j) * 33 + o;
                res[j] = red[idx] + red[TT * 33 + idx] + bv;
            }
            float* op = out + ((size_t)n * OO + o_base + o) * TT + t0;
            __builtin_memcpy(__builtin_assume_aligned(op, 16), &res, 16);
        }
        __syncthreads();   // red reads drained before next oc's stage1 writes kern region
    }
}

extern "C" void kernel_launch(void* const* d_in, const int* in_sizes, int n_in,
                              void* d_out, int out_size, void* d_ws, size_t ws_size,
                              hipStream_t stream) {
    const float* pept = (const float*)d_in[0];
    const float* mhc  = (const float*)d_in[1];
    const float* wgt  = (const float*)d_in[2];
    const float* bias = (const float*)d_in[3];
    float* out = (float*)d_out;
    dim3 block(256);             // 4 waves

    const size_t w_bytes = (size_t)OO * KK * WPADL * sizeof(u16); // 294,912
    if (ws_size >= w_bytes) {
        w_convert<<<dim3((OO * KK * (WPADL / 2) + 255) / 256), block, 0, stream>>>(wgt, (u32*)d_ws);
        iconv_kernel<true><<<dim3(NN * 4), block, 0, stream>>>(pept, mhc, wgt, (const u16*)d_ws, bias, out);
    } else {
        iconv_kernel<false><<<dim3(NN * 4), block, 0, stream>>>(pept, mhc, wgt, nullptr, bias, out);
    }
}

// Round 3
// 143.921 us; speedup vs baseline: 1.4849x; 1.1746x over previous
//
#include <hip/hip_runtime.h>
#include <hip/hip_bf16.h>

typedef unsigned short u16;
typedef unsigned int u32;
typedef __bf16 bf16x8 __attribute__((ext_vector_type(8)));
typedef float f32x4 __attribute__((ext_vector_type(4)));
typedef unsigned int u32x4 __attribute__((ext_vector_type(4)));
typedef unsigned int u32x2 __attribute__((ext_vector_type(2)));

#define NN 512
#define LL 40
#define DD 128
#define OO 256
#define KK 9
#define MHCL 34
#define TT 32
#define OC 32      // o-chunk per oc-iteration
#define OCPG 4     // oc iterations per group (2 groups -> all 8 per sample-block)
#define PSTR 136   // pept LDS row stride (u16)
#define MSTR 72    // mhcT LDS row stride (u16)
#define KSTR 136   // kern LDS row stride (u16)
#define LPAD 64    // padded l-dim for MFMA K
#define WPADL 64   // padded l-dim in preconverted W

#define PEPT_U16 (LL * PSTR)   // 5440 u16 = 10880 B
#define KERN_U16 (32 * KSTR)   // 4352 u16 = 8704 B per group (holds red2 f32[2][32][33]=8448B too)

__device__ __forceinline__ u16 f2bf(float x) {
    unsigned int u = __builtin_bit_cast(unsigned int, x);
    u = (u + 0x7FFFu + ((u >> 16) & 1u)) >> 16;
    return (u16)u;
}
__device__ __forceinline__ u32 pk2(float a, float b) {
    __hip_bfloat162 h = __float22bfloat162_rn(make_float2(a, b)); // x = low half
    u32 r;
    __builtin_memcpy(&r, &h, 4);
    return r;
}
__device__ __forceinline__ bf16x8 lds_read8(const u16* p) {
    u32x4 r;
    __builtin_memcpy(&r, __builtin_assume_aligned(p, 16), 16);
    return __builtin_bit_cast(bf16x8, r);
}
__device__ __forceinline__ f32x4 mfma16(bf16x8 a, bf16x8 b, f32x4 c) {
    return __builtin_amdgcn_mfma_f32_16x16x32_bf16(a, b, c, 0, 0, 0);
}

// prologue: W fp32 [O][K][34] -> bf16 zero-padded [O][K][64] in ws
__global__ void w_convert(const float* __restrict__ wgt, u32* __restrict__ wp) {
    int i = blockIdx.x * 256 + threadIdx.x;        // 36864 u32 outputs
    if (i >= OO * KK * (WPADL / 2)) return;
    int o = i / (KK * (WPADL / 2));
    int r = i - o * (KK * (WPADL / 2));
    int k = r >> 5;
    int lp = (r & 31) << 1;
    const float* src = wgt + ((size_t)o * KK + k) * MHCL;
    float a = (lp     < MHCL) ? src[lp]     : 0.f;
    float b = (lp + 1 < MHCL) ? src[lp + 1] : 0.f;
    wp[i] = pk2(a, b);
}

// One 512-thread block per sample: shared prologue (staged once), two
// independent 4-wave groups each running the round-0 engine on 4 o-chunks
// with a private kern buffer. R0/R2 fit: per-block overhead was 38% of wall
// (82=1024p+4096c, 113=2048p+4096c -> 1024p=31us); this halves executions
// and halves per-execution staging chain, keeping 16 waves/CU (2 blocks x 8).
// launch_bounds(512,4): VGPR cap 128 (cap 64 spilled in R1: WRITE 16->203MB).
template<bool PRE>
__global__ __launch_bounds__(512, 4)
void iconv_kernel(const float* __restrict__ pept,
                  const float* __restrict__ mhc,
                  const float* __restrict__ wgt,
                  const u16* __restrict__ wp,
                  const float* __restrict__ bias,
                  float* __restrict__ out)
{
    // LDS: 10880 + 2*8704 = 28288 B -> 5 blocks/CU by LDS, 2 by grid/waves.
    // Union lifetimes: [0,18432) mhcT[128][72] (staging only, < kern1 base 19584) ->
    //   [0,10880) pept[40][136] | per-group kern[32][136] / red2 f32[2][32][33]
    __shared__ __align__(16) u16 s_mem[PEPT_U16 + 2 * KERN_U16];

    const int tid  = threadIdx.x;
    const int wave = tid >> 6;
    const int grp  = wave >> 2;     // 0: o-chunks 0..3, 1: o-chunks 4..7
    const int wl   = wave & 3;      // wave-in-group = d-chunk owner
    const int lane = tid & 63;
    const int quad = lane >> 4;
    const int l16  = lane & 15;

    const int n = blockIdx.x;       // 1 block per sample

    u16* const s_pept = s_mem;
    u16* const kb     = s_mem + PEPT_U16 + grp * KERN_U16;

    auto loadW = [&](int o_base, int k, bf16x8 wF[2][2]) {
        if (PRE) {
            #pragma unroll
            for (int mt = 0; mt < 2; ++mt) {
                const u16* wr = wp + ((size_t)(o_base + mt * 16 + l16) * KK + k) * WPADL;
                u32x4 r0, r1;
                __builtin_memcpy(&r0, __builtin_assume_aligned(wr + quad * 8, 16), 16);
                __builtin_memcpy(&r1, __builtin_assume_aligned(wr + 32 + quad * 8, 16), 16);
                wF[mt][0] = __builtin_bit_cast(bf16x8, r0);
                wF[mt][1] = __builtin_bit_cast(bf16x8, r1);
            }
        } else {
            #pragma unroll
            for (int mt = 0; mt < 2; ++mt) {
                const float* wrow = wgt + ((size_t)(o_base + mt * 16 + l16) * KK + k) * MHCL;
                float w8[8];
                __builtin_memcpy(w8, __builtin_assume_aligned(wrow + quad * 8, 8), 32);
                u16 h0[8];
                #pragma unroll
                for (int j = 0; j < 8; ++j) h0[j] = f2bf(w8[j]);
                __builtin_memcpy(&wF[mt][0], h0, 16);
                u16 h1[8] = {0,0,0,0,0,0,0,0};
                if (quad == 0) { h1[0] = f2bf(wrow[32]); h1[1] = f2bf(wrow[33]); }
                __builtin_memcpy(&wF[mt][1], h1, 16);
            }
        }
    };

    // hoist this group's first W-fragment load above the prologue: its global
    // latency hides under staging instead of heading the first k-loop.
    bf16x8 wFh[2][2];
    loadW((grp * OCPG) * OC, 0, wFh);

    // ---- stage A: mhcT [128][MSTR] bf16, l zero-padded to 64, vectorized b128 writes ----
    {
        const float* mg = mhc + (size_t)n * MHCL * DD;
        #pragma unroll 1
        for (int i = tid; i < DD * (LPAD / 8); i += 512) {   // 1024 items, g wave-uniform
            int g = i >> 7, d = i & 127;
            u32x4 hh;
            #pragma unroll
            for (int jj = 0; jj < 4; ++jj) {
                int l = g * 8 + jj * 2;
                float a = (l     < MHCL) ? mg[(size_t)l * DD + d]       : 0.f;
                float b = (l + 1 < MHCL) ? mg[(size_t)(l + 1) * DD + d] : 0.f;
                hh[jj] = pk2(a, b);
            }
            __builtin_memcpy(__builtin_assume_aligned(&s_mem[d * MSTR + g * 8], 16), &hh, 16);
        }
    }
    __syncthreads();

    // ---- k-invariant mhc A-fragments: group's wave wl owns d in [wl*32, wl*32+32) ----
    bf16x8 aF[2][2];   // [nt-local][ki]; A[m=d][kdim=l]
    #pragma unroll
    for (int ntl = 0; ntl < 2; ++ntl) {
        const int d = (wl * 2 + ntl) * 16 + l16;
        aF[ntl][0] = lds_read8(&s_mem[d * MSTR + quad * 8]);
        aF[ntl][1] = lds_read8(&s_mem[d * MSTR + 32 + quad * 8]);
    }
    __syncthreads();   // mhcT region dead -> pept + kern buffers may overwrite

    // ---- stage B: pept fp32 -> bf16 ----
    {
        const float* pg = pept + (size_t)n * LL * DD;
        #pragma unroll 1
        for (int i = tid; i < (LL * DD) / 4; i += 512) {
            int row = i >> 5, c4 = (i & 31) << 2;
            f32x4 v;
            __builtin_memcpy(&v, __builtin_assume_aligned(pg + row * DD + c4, 16), 16);
            u32x2 h = { pk2(v[0], v[1]), pk2(v[2], v[3]) };
            __builtin_memcpy(__builtin_assume_aligned(&s_pept[row * PSTR + c4], 8), &h, 8);
        }
    }
    __syncthreads();

    // stage1: wave computes kern rows (all o') for its d-columns [32*wl, 32*wl+32) — group-private region
    auto stage1 = [&](const bf16x8 wF[2][2]) {
        #pragma unroll
        for (int ntl = 0; ntl < 2; ++ntl) {
            const int nt = wl * 2 + ntl;
            f32x4 c0 = {0.f,0.f,0.f,0.f}, c1 = c0;
            #pragma unroll
            for (int ki = 0; ki < 2; ++ki) {
                c0 = mfma16(aF[ntl][ki], wF[0][ki], c0);   // C[d_local][o' 0..15]
                c1 = mfma16(aF[ntl][ki], wF[1][ki], c1);   // C[d_local][o' 16..31]
            }
            u32x2 p0 = { pk2(fmaxf(c0[0], 0.f), fmaxf(c0[1], 0.f)),
                         pk2(fmaxf(c0[2], 0.f), fmaxf(c0[3], 0.f)) };
            u32x2 p1 = { pk2(fmaxf(c1[0], 0.f), fmaxf(c1[1], 0.f)),
                         pk2(fmaxf(c1[2], 0.f), fmaxf(c1[3], 0.f)) };
            __builtin_memcpy(__builtin_assume_aligned(&kb[l16 * KSTR + nt * 16 + quad * 4], 8), &p0, 8);
            __builtin_memcpy(__builtin_assume_aligned(&kb[(16 + l16) * KSTR + nt * 16 + quad * 4], 8), &p1, 8);
        }
    };

    const int off = wl * 32 + quad * 8;   // this wave's d-chunk column offset

    #pragma unroll 1
    for (int oci = 0; oci < OCPG; ++oci) {
        const int o_base = (grp * OCPG + oci) * OC;
        // acc_ij[r] = out[t = i*16 + quad*4 + r][o' = j*16 + l16], partial over d-chunk = wl
        f32x4 acc00 = {0.f,0.f,0.f,0.f}, acc01 = acc00, acc10 = acc00, acc11 = acc00;

        stage1(wFh);   // k=0 fragments preloaded (kernel top / previous epilogue)

        // NO barriers: wave reads exactly the kern columns it wrote; same-wave LDS deps
        // are ordered by the LDS pipe. Waves drift freely -> latency pipelining across k.
        for (int k = 0; k < KK; ++k) {
            bf16x8 wFn[2][2];
            if (k < KK - 1) loadW(o_base, k + 1, wFn);   // issue global loads early
            // stage 2: A=pept (m=t), B=kern (n=o'), kdim = this wave's 32 d
            bf16x8 bk0 = lds_read8(&kb[l16 * KSTR + off]);
            bf16x8 bk1 = lds_read8(&kb[(16 + l16) * KSTR + off]);
            bf16x8 ap0 = lds_read8(&s_pept[(k + l16) * PSTR + off]);
            bf16x8 ap1 = lds_read8(&s_pept[(k + 16 + l16) * PSTR + off]);
            acc00 = mfma16(ap0, bk0, acc00);
            acc01 = mfma16(ap0, bk1, acc01);
            acc10 = mfma16(ap1, bk0, acc10);
            acc11 = mfma16(ap1, bk1, acc11);
            if (k < KK - 1) stage1(wFn);                 // overwrite own columns for k+1
        }

        // prefetch next oc's k=0 W fragments: latency hides under the reduction
        if (oci + 1 < OCPG) loadW((grp * OCPG + oci + 1) * OC, 0, wFh);

        __syncthreads();   // all waves done with kern/stage2 before red2 tramples kb
        // ---- cross-wave (d-chunk) reduction, 2-step into red2 = f32[2][t=32][o'=33] ----
        float* red = (float*)kb;
        if (wl < 2) {
            float* rw = red + wl * (TT * 33);
            #pragma unroll
            for (int r = 0; r < 4; ++r) {
                rw[(quad * 4 + r) * 33 + l16]           = acc00[r];
                rw[(quad * 4 + r) * 33 + 16 + l16]      = acc01[r];
                rw[(16 + quad * 4 + r) * 33 + l16]      = acc10[r];
                rw[(16 + quad * 4 + r) * 33 + 16 + l16] = acc11[r];
            }
        }
        __syncthreads();
        if (wl >= 2) {     // disjoint buffers: wl2 -> buf0, wl3 -> buf1 (race-free RMW)
            float* rw = red + (wl - 2) * (TT * 33);
            #pragma unroll
            for (int r = 0; r < 4; ++r) {
                rw[(quad * 4 + r) * 33 + l16]           += acc00[r];
                rw[(quad * 4 + r) * 33 + 16 + l16]      += acc01[r];
                rw[(16 + quad * 4 + r) * 33 + l16]      += acc10[r];
                rw[(16 + quad * 4 + r) * 33 + 16 + l16] += acc11[r];
            }
        }
        __syncthreads();

        {
            const int lt = tid & 255;       // group-local thread id
            const int o  = lt >> 3;         // 0..31
            const int t0 = (lt & 7) * 4;    // 0,4,...,28
            const float bv = bias[o_base + o];
            f32x4 res;
            #pragma unroll
            for (int j = 0; j < 4; ++j) {
                int idx = (t0 + j) * 33 + o;
                res[j] = red[idx] + red[TT * 33 + idx] + bv;
            }
            float* op = out + ((size_t)n * OO + o_base + o) * TT + t0;
            __builtin_memcpy(__builtin_assume_aligned(op, 16), &res, 16);
        }
        __syncthreads();   // red reads drained before next oc's stage1 writes kern region
    }
}

extern "C" void kernel_launch(void* const* d_in, const int* in_sizes, int n_in,
                              void* d_out, int out_size, void* d_ws, size_t ws_size,
                              hipStream_t stream) {
    const float* pept = (const float*)d_in[0];
    const float* mhc  = (const float*)d_in[1];
    const float* wgt  = (const float*)d_in[2];
    const float* bias = (const float*)d_in[3];
    float* out = (float*)d_out;

    const size_t w_bytes = (size_t)OO * KK * WPADL * sizeof(u16); // 294,912
    if (ws_size >= w_bytes) {
        w_convert<<<dim3((OO * KK * (WPADL / 2) + 255) / 256), dim3(256), 0, stream>>>(wgt, (u32*)d_ws);
        iconv_kernel<true><<<dim3(NN), dim3(512), 0, stream>>>(pept, mhc, wgt, (const u16*)d_ws, bias, out);
    } else {
        iconv_kernel<false><<<dim3(NN), dim3(512), 0, stream>>>(pept, mhc, wgt, nullptr, bias, out);
    }
}